// Round 2
// baseline (93.059 us; speedup 1.0000x reference)
//
#include <hip/hip_runtime.h>
#include <hip/hip_bf16.h>

// Problem: out[b, 2t+r, c*128+d] = normed outer product of x[b,t,:] with itself.
// Key identity: ||flatten(w*x⊗x)||_2 = |w| * (Σ x_c^2), so the per-frame work is
// a 128-elem sum of squares + a rank-1 outer product written twice (UpSampling1D).
// Memory-bound: 512 MiB of fp32 writes, 2 MiB of reads.

#define C 128
#define CC (C * C)       // 16384
#define CC4 (CC / 4)     // 4096 float4 per time-row
#define NTHREADS 256
#define EPS 1e-12f

typedef float f32x4 __attribute__((ext_vector_type(4)));  // native vector: OK for nontemporal builtins

__global__ __launch_bounds__(NTHREADS) void frame_outer_kernel(
    const float* __restrict__ x,   // (BT, 128)
    const float* __restrict__ w,   // (1,)
    float* __restrict__ out)       // (BT*2, 16384)
{
    __shared__ __align__(16) float xs[C];   // x row
    __shared__ float as[C];                 // a[c] = w * x[c] * rs
    __shared__ float partials[4];

    const int frame = blockIdx.x;
    const int tid = threadIdx.x;
    const float* __restrict__ xrow = x + (size_t)frame * C;

    // Load x row (threads 0..127) and accumulate sum of squares.
    float v = 0.0f;
    if (tid < C) {
        v = xrow[tid];
        xs[tid] = v;
    }
    float p = v * v;
    // wave64 shuffle reduction
    #pragma unroll
    for (int off = 32; off > 0; off >>= 1)
        p += __shfl_down(p, off);
    if ((tid & 63) == 0) partials[tid >> 6] = p;
    __syncthreads();

    const float S = partials[0] + partials[1] + partials[2] + partials[3];
    const float wv = w[0];
    const float ws = wv * S;
    const float rs = rsqrtf(fmaxf(ws * ws, EPS));

    if (tid < C) as[tid] = wv * xs[tid] * rs;
    __syncthreads();

    // Stream the outer product: out[c*128 + d] = as[c] * xs[d], written to
    // time rows 2t and 2t+1 (frame index bt maps to rows 2*bt, 2*bt+1).
    const f32x4* __restrict__ x4 = (const f32x4*)xs;
    float* __restrict__ obase = out + (size_t)frame * 2 * CC;
    f32x4* __restrict__ o0 = (f32x4*)obase;
    f32x4* __restrict__ o1 = (f32x4*)(obase + CC);

    #pragma unroll
    for (int k = 0; k < CC4 / NTHREADS; ++k) {      // 16 iterations
        const int i = k * NTHREADS + tid;           // float4 index in row
        const int c = i >> 5;                       // row of outer product
        const int d4 = i & 31;                      // float4 col
        const float a = as[c];
        const f32x4 xv = x4[d4];
        f32x4 r = a * xv;
        __builtin_nontemporal_store(r, o0 + i);
        __builtin_nontemporal_store(r, o1 + i);
    }
}

extern "C" void kernel_launch(void* const* d_in, const int* in_sizes, int n_in,
                              void* d_out, int out_size, void* d_ws, size_t ws_size,
                              hipStream_t stream) {
    const float* x = (const float*)d_in[0];
    const float* w = (const float*)d_in[1];
    float* out = (float*)d_out;

    const int BT = in_sizes[0] / C;  // 8 * 512 = 4096 frames
    frame_outer_kernel<<<BT, NTHREADS, 0, stream>>>(x, w, out);
}